// Round 2
// baseline (7182.378 us; speedup 1.0000x reference)
//
#include <hip/hip_runtime.h>
#include <math.h>

// Problem constants
#define B_ 64
#define S_ 64
#define E_ 256
#define H_ 512
#define V_ 50000
#define T_ 32
#define SOS_ 1
#define NCHUNK 196           // ceil(50000/256)
static const long long LDCV = (long long)T_ * V_;   // out row stride (per batch)

typedef unsigned short u16;
typedef u16   u16x8  __attribute__((ext_vector_type(8)));
typedef short bf16x8 __attribute__((ext_vector_type(8)));
typedef float f32x4  __attribute__((ext_vector_type(4)));

static __device__ __forceinline__ u16 f2bf(float f) {
    unsigned u = __float_as_uint(f);
    unsigned r = (u + 0x7FFFu + ((u >> 16) & 1u)) >> 16;
    return (u16)r;
}

// ---------------------------------------------------------------------------
// Setup kernels
// ---------------------------------------------------------------------------
__global__ __launch_bounds__(256) void build_wbig(
    const float* __restrict__ w_ih, const float* __restrict__ w_hh,
    const float* __restrict__ b_ih, const float* __restrict__ b_hh,
    float* __restrict__ WbigT, float* __restrict__ biasBig)
{
    int g = blockIdx.x * 256 + threadIdx.x;
    if (g < 2048 * 768) {
        int n = g / 768, k = g % 768;
        int j = n >> 2, c = n & 3;
        float v = 0.f;
        if (c == 0)      v = (k < 256) ? w_ih[j * 256 + k]          : w_hh[j * 512 + (k - 256)];
        else if (c == 1) v = (k < 256) ? w_ih[(512 + j) * 256 + k]  : w_hh[(512 + j) * 512 + (k - 256)];
        else if (c == 2) v = (k < 256) ? w_ih[(1024 + j) * 256 + k] : 0.f;
        else             v = (k < 256) ? 0.f                        : w_hh[(1024 + j) * 512 + (k - 256)];
        WbigT[g] = v;
    }
    if (g < 2048) {
        int j = g >> 2, c = g & 3;
        float bv;
        if (c == 0)      bv = b_ih[j] + b_hh[j];
        else if (c == 1) bv = b_ih[512 + j] + b_hh[512 + j];
        else if (c == 2) bv = b_ih[1024 + j];
        else             bv = b_hh[1024 + j];
        biasBig[g] = bv;
    }
}

__global__ __launch_bounds__(256) void transpose_aw(
    const float* __restrict__ attn_w, float* __restrict__ awT)
{
    int idx = blockIdx.x * 256 + threadIdx.x;
    int h = idx >> 9, g = idx & 511;
    awT[idx] = attn_w[g * 512 + h];
}

__global__ __launch_bounds__(256) void init_state(
    const float* __restrict__ enc_hidden, float* __restrict__ hbuf0,
    int* __restrict__ dec_in)
{
    int idx = blockIdx.x * 256 + threadIdx.x;
    if (idx < B_ * H_) hbuf0[idx] = enc_hidden[idx];
    if (idx < B_) dec_in[idx] = SOS_;
}

// fc_w fp32 -> bf16 (one-time)
__global__ __launch_bounds__(256) void conv_fcw(
    const float* __restrict__ fc_w, u16* __restrict__ fcwb)
{
    size_t i = (size_t)(blockIdx.x * 256 + threadIdx.x) * 8;
    float4 a = *(const float4*)&fc_w[i];
    float4 b = *(const float4*)&fc_w[i + 4];
    u16x8 o;
    o[0] = f2bf(a.x); o[1] = f2bf(a.y); o[2] = f2bf(a.z); o[3] = f2bf(a.w);
    o[4] = f2bf(b.x); o[5] = f2bf(b.y); o[6] = f2bf(b.z); o[7] = f2bf(b.w);
    *(u16x8*)&fcwb[i] = o;
}

// ---------------------------------------------------------------------------
// Generic 64x64x(K) fp32 tiled GEMM.  C[m][n] = sum_k A[m][k] * W[n][k]
// MODE 0: A(m,k) = k<256 ? emb[tok[m]][k] : hcur[m][k-256]  (gates; partials)
// MODE 1: A = plain [64][Kfull]; C = partials per K-chunk (blockIdx.y)
// MODE 2: A = plain, single K chunk; C[m*ldc + n] = acc + bias[n] (fallback)
// ---------------------------------------------------------------------------
template <int MODE>
__global__ __launch_bounds__(256) void gemm64(
    const float* __restrict__ A, const float* __restrict__ W,
    float* __restrict__ C, const float* __restrict__ bias,
    int N, int Kfull, int kchunk,
    const float* __restrict__ emb, const int* __restrict__ tok,
    const float* __restrict__ hcur, long long ldc)
{
    __shared__ float As[64][68];
    __shared__ float Ws[64][68];
    const int tid = threadIdx.x;
    const int n0 = blockIdx.x * 64;
    const int k0base = blockIdx.y * kchunk;
    const int tm = tid & 15;
    const int tn = tid >> 4;
    float acc[4][4] = {{0.f}};

    for (int kt = 0; kt < kchunk; kt += 64) {
        const int k0 = k0base + kt;
        #pragma unroll
        for (int r = 0; r < 4; ++r) {
            int idx = tid + r * 256;
            int m = idx >> 4;
            int kk = (idx & 15) << 2;
            float4 v;
            if (MODE == 0) {
                int k = k0 + kk;
                if (k < 256) v = *(const float4*)&emb[(size_t)tok[m] * 256 + k];
                else         v = *(const float4*)&hcur[m * 512 + (k - 256)];
            } else {
                v = *(const float4*)&A[(size_t)m * Kfull + k0 + kk];
            }
            As[kk + 0][m] = v.x; As[kk + 1][m] = v.y;
            As[kk + 2][m] = v.z; As[kk + 3][m] = v.w;
        }
        #pragma unroll
        for (int r = 0; r < 4; ++r) {
            int idx = tid + r * 256;
            int n = idx >> 4;
            int kk = (idx & 15) << 2;
            int row = n0 + n;
            float4 v = make_float4(0.f, 0.f, 0.f, 0.f);
            if (MODE != 2 || row < N)
                v = *(const float4*)&W[(size_t)row * Kfull + k0 + kk];
            Ws[kk + 0][n] = v.x; Ws[kk + 1][n] = v.y;
            Ws[kk + 2][n] = v.z; Ws[kk + 3][n] = v.w;
        }
        __syncthreads();
        #pragma unroll
        for (int kk = 0; kk < 64; ++kk) {
            float4 a = *(const float4*)&As[kk][tm << 2];
            float4 w = *(const float4*)&Ws[kk][tn << 2];
            acc[0][0] += a.x * w.x; acc[0][1] += a.x * w.y;
            acc[0][2] += a.x * w.z; acc[0][3] += a.x * w.w;
            acc[1][0] += a.y * w.x; acc[1][1] += a.y * w.y;
            acc[1][2] += a.y * w.z; acc[1][3] += a.y * w.w;
            acc[2][0] += a.z * w.x; acc[2][1] += a.z * w.y;
            acc[2][2] += a.z * w.z; acc[2][3] += a.z * w.w;
            acc[3][0] += a.w * w.x; acc[3][1] += a.w * w.y;
            acc[3][2] += a.w * w.z; acc[3][3] += a.w * w.w;
        }
        __syncthreads();
    }

    if (MODE == 2) {
        #pragma unroll
        for (int i = 0; i < 4; ++i) {
            int m = (tm << 2) + i;
            #pragma unroll
            for (int j2 = 0; j2 < 4; ++j2) {
                int v = n0 + (tn << 2) + j2;
                if (v < N) C[(long long)m * ldc + v] = acc[i][j2] + bias[v];
            }
        }
    } else {
        float* Cp = C + (size_t)blockIdx.y * 64 * N;
        #pragma unroll
        for (int i = 0; i < 4; ++i) {
            int m = (tm << 2) + i;
            #pragma unroll
            for (int j2 = 0; j2 < 4; ++j2) {
                Cp[(size_t)m * N + n0 + (tn << 2) + j2] = acc[i][j2];
            }
        }
    }
}

// ---------------------------------------------------------------------------
// GRU gate combine (6 K-partials)
// ---------------------------------------------------------------------------
__global__ __launch_bounds__(512) void combine_kernel(
    const float* __restrict__ gP, const float* __restrict__ bb,
    const float* __restrict__ hcur, float* __restrict__ hnxt,
    float* __restrict__ concatA)
{
    int idx = blockIdx.x * 512 + threadIdx.x;
    int b = idx >> 9, j = idx & 511;
    int base = b * 2048 + (j << 2);
    const int SP = 64 * 2048;
    float g0 = bb[(j << 2) + 0], g1 = bb[(j << 2) + 1];
    float g2 = bb[(j << 2) + 2], g3 = bb[(j << 2) + 3];
    #pragma unroll
    for (int p = 0; p < 6; ++p) {
        g0 += gP[p * SP + base + 0];
        g1 += gP[p * SP + base + 1];
        g2 += gP[p * SP + base + 2];
        g3 += gP[p * SP + base + 3];
    }
    float r = 1.f / (1.f + expf(-g0));
    float z = 1.f / (1.f + expf(-g1));
    float n = tanhf(g2 + r * g3);
    float hv = hcur[idx];
    float h2 = (1.f - z) * n + z * hv;
    hnxt[idx] = h2;
    concatA[b * 1024 + j] = h2;
}

// ---------------------------------------------------------------------------
// Attention (q from 4 K-partials)
// ---------------------------------------------------------------------------
__global__ __launch_bounds__(512) void attn_kernel(
    const float* __restrict__ qP, const float* __restrict__ enc,
    float* __restrict__ concatA)
{
    int b = blockIdx.x;
    int tid = threadIdx.x;
    __shared__ float q[512];
    __shared__ float aw[64];
    const int SP = 64 * 512;
    q[tid] = qP[b * 512 + tid] + qP[SP + b * 512 + tid]
           + qP[2 * SP + b * 512 + tid] + qP[3 * SP + b * 512 + tid];
    __syncthreads();

    int wv = tid >> 6, ln = tid & 63;
    #pragma unroll
    for (int si = 0; si < 8; ++si) {
        int s = (wv << 3) + si;
        const float* er = enc + ((size_t)(b * 64 + s)) * 512;
        float p = 0.f;
        #pragma unroll
        for (int i = 0; i < 8; ++i) p += q[ln + (i << 6)] * er[ln + (i << 6)];
        for (int off = 32; off; off >>= 1) p += __shfl_down(p, off);
        if (ln == 0) aw[s] = p;
    }
    __syncthreads();
    if (tid < 64) {
        float v = aw[tid], m = v;
        for (int off = 32; off; off >>= 1) m = fmaxf(m, __shfl_xor(m, off));
        float e = expf(v - m);
        float ssum = e;
        for (int off = 32; off; off >>= 1) ssum += __shfl_xor(ssum, off);
        aw[tid] = e / ssum;
    }
    __syncthreads();
    float c = 0.f;
    const float* eb = enc + (size_t)b * 64 * 512 + tid;
    for (int s = 0; s < 64; ++s) c += aw[s] * eb[s * 512];
    concatA[b * 1024 + 512 + tid] = c;
}

// tanh of 8 K-partials; writes fp32 + bf16 copies
__global__ __launch_bounds__(512) void tanh_combine(
    const float* __restrict__ cgP, float* __restrict__ Abuf,
    u16* __restrict__ Abufb)
{
    int idx = blockIdx.x * 512 + threadIdx.x;
    const int SP = 64 * 512;
    float v = 0.f;
    #pragma unroll
    for (int p = 0; p < 8; ++p) v += cgP[p * SP + idx];
    float th = tanhf(v);
    Abuf[idx] = th;
    Abufb[idx] = f2bf(th);
}

// ---------------------------------------------------------------------------
// Logits GEMM via bf16 MFMA. Block = 256 thr (4 waves), tile 64 x 256.
// Writes raw biased logits to out, plus per-chunk (max, argmax, sumexp).
// ---------------------------------------------------------------------------
__global__ __launch_bounds__(256) void logits_mfma(
    const u16* __restrict__ Abufb, const u16* __restrict__ fcwb,
    const float* __restrict__ fc_b, float* __restrict__ outp,   // out + t*V_
    float* __restrict__ pmax, int* __restrict__ pidx, float* __restrict__ psum)
{
    __shared__ u16 sA[64 * 512];     // 64KB, XOR-swizzled; reused for reductions
    const int tid = threadIdx.x;
    const int wv = tid >> 6, lane = tid & 63;
    const int nb = blockIdx.x * 256;
    const int col16 = lane & 15, grp = lane >> 4;

    // stage A with swizzle: byte(m,k) = m*1024 + ((k*2) ^ ((m&7)<<4))
    #pragma unroll
    for (int i = 0; i < 16; ++i) {
        int c = tid + i * 256;          // 16B chunk id
        int m = c >> 6;
        int cb = (c & 63) << 4;
        int sb = cb ^ ((m & 7) << 4);
        *(u16x8*)((char*)sA + m * 1024 + sb) =
            *(const u16x8*)(Abufb + m * 512 + (cb >> 1));
    }
    __syncthreads();

    int nfb[4]; bool val[4];
    #pragma unroll
    for (int fn = 0; fn < 4; ++fn) {
        nfb[fn] = nb + wv * 64 + fn * 16;
        val[fn] = nfb[fn] < V_;          // V_ % 16 == 0: frag all-in or all-out
    }
    const u16* wptr[4];
    #pragma unroll
    for (int fn = 0; fn < 4; ++fn) {
        size_t rowi = val[fn] ? (size_t)(nfb[fn] + col16) : 0;
        wptr[fn] = fcwb + rowi * 512 + (grp << 3);
    }

    f32x4 acc[4][4];
    #pragma unroll
    for (int a = 0; a < 4; ++a)
        #pragma unroll
        for (int b2 = 0; b2 < 4; ++b2) acc[a][b2] = (f32x4){0.f, 0.f, 0.f, 0.f};

    bf16x8 bcur[4];
    #pragma unroll
    for (int fn = 0; fn < 4; ++fn) bcur[fn] = *(const bf16x8*)(wptr[fn]);

    for (int kt = 0; kt < 16; ++kt) {
        bf16x8 bnxt[4];
        int ktn = (kt + 1 < 16) ? kt + 1 : 15;
        #pragma unroll
        for (int fn = 0; fn < 4; ++fn)
            bnxt[fn] = *(const bf16x8*)(wptr[fn] + ktn * 32);
        bf16x8 af[4];
        int kb = kt * 64 + (grp << 4);
        #pragma unroll
        for (int fm = 0; fm < 4; ++fm) {
            int mg = fm * 16 + col16;
            af[fm] = *(const bf16x8*)((const char*)sA + mg * 1024 + (kb ^ ((mg & 7) << 4)));
        }
        #pragma unroll
        for (int fm = 0; fm < 4; ++fm)
            #pragma unroll
            for (int fn = 0; fn < 4; ++fn)
                acc[fm][fn] = __builtin_amdgcn_mfma_f32_16x16x32_bf16(
                    af[fm], bcur[fn], acc[fm][fn], 0, 0, 0);
        #pragma unroll
        for (int fn = 0; fn < 4; ++fn) bcur[fn] = bnxt[fn];
    }
    __syncthreads();   // all A reads done; sA reused below

    float* wmaxp = (float*)sA;            // [4][64]
    int*   widxp = (int*)(sA + 512);      // byte 1024
    float* wsump = (float*)(sA + 1024);   // byte 2048

    float bias[4];
    #pragma unroll
    for (int fn = 0; fn < 4; ++fn) bias[fn] = val[fn] ? fc_b[nfb[fn] + col16] : 0.f;

    #pragma unroll
    for (int fm = 0; fm < 4; ++fm) {
        #pragma unroll
        for (int r = 0; r < 4; ++r) {
            int mrow = fm * 16 + grp * 4 + r;
            float best = -INFINITY; int bi = 0;
            float vv[4];
            #pragma unroll
            for (int fn = 0; fn < 4; ++fn) {
                float v = -INFINITY;
                if (val[fn]) {
                    v = acc[fm][fn][r] + bias[fn];
                    int n = nfb[fn] + col16;
                    outp[(size_t)mrow * LDCV + n] = v;
                    if (v > best || (v == best && n < bi)) { best = v; bi = n; }
                }
                vv[fn] = v;
            }
            #pragma unroll
            for (int d = 1; d < 16; d <<= 1) {
                float ov = __shfl_xor(best, d); int oi = __shfl_xor(bi, d);
                if (ov > best || (ov == best && oi < bi)) { best = ov; bi = oi; }
            }
            float s = 0.f;
            #pragma unroll
            for (int fn = 0; fn < 4; ++fn)
                if (val[fn]) s += __expf(vv[fn] - best);
            #pragma unroll
            for (int d = 1; d < 16; d <<= 1) s += __shfl_xor(s, d);
            if (col16 == 0) {
                wmaxp[wv * 64 + mrow] = best;
                widxp[wv * 64 + mrow] = bi;
                wsump[wv * 64 + mrow] = s;
            }
        }
    }
    __syncthreads();
    if (tid < 64) {
        float gm = -INFINITY; int gi = 0;
        #pragma unroll
        for (int w = 0; w < 4; ++w) {
            float v = wmaxp[w * 64 + tid]; int ii = widxp[w * 64 + tid];
            if (v > gm || (v == gm && ii < gi)) { gm = v; gi = ii; }
        }
        float gs = 0.f;
        #pragma unroll
        for (int w = 0; w < 4; ++w)
            gs += wsump[w * 64 + tid] * __expf(wmaxp[w * 64 + tid] - gm);
        pmax[tid * NCHUNK + blockIdx.x] = gm;
        pidx[tid * NCHUNK + blockIdx.x] = gi;
        psum[tid * NCHUNK + blockIdx.x] = gs;
    }
}

// ---------------------------------------------------------------------------
// Combine partials -> logZ; fp32-exact argmax over candidate chunks -> dec_in
// ---------------------------------------------------------------------------
__global__ __launch_bounds__(256) void szrefine(
    const float* __restrict__ pmax, const int* __restrict__ pidx,
    const float* __restrict__ psum, const float* __restrict__ Abuf,
    const float* __restrict__ fc_w, const float* __restrict__ fc_b,
    float* __restrict__ logZ_arr, int* __restrict__ dec_in)
{
    int b = blockIdx.x, tid = threadIdx.x;
    __shared__ float sv[256];
    __shared__ int   si2[256];
    __shared__ float A[512];
    __shared__ int clist[96];
    __shared__ int ccnt;

    float pm = (tid < NCHUNK) ? pmax[b * NCHUNK + tid] : -INFINITY;
    sv[tid] = pm; __syncthreads();
    for (int st = 128; st; st >>= 1) { if (tid < st) sv[tid] = fmaxf(sv[tid], sv[tid + st]); __syncthreads(); }
    float Mb = sv[0]; __syncthreads();

    float sc = (tid < NCHUNK) ? psum[b * NCHUNK + tid] * __expf(pm - Mb) : 0.f;
    sv[tid] = sc; __syncthreads();
    for (int st = 128; st; st >>= 1) { if (tid < st) sv[tid] += sv[tid + st]; __syncthreads(); }
    if (tid == 0) { logZ_arr[b] = Mb + logf(sv[0]); ccnt = 0; }
    __syncthreads();

    if (tid < NCHUNK && pm >= Mb - 0.05f) {
        int s2 = atomicAdd(&ccnt, 1);
        if (s2 < 96) clist[s2] = tid;
    }
    A[tid] = Abuf[b * 512 + tid];
    A[tid + 256] = Abuf[b * 512 + 256 + tid];
    __syncthreads();

    int nc = min(ccnt, 96);
    float best = -INFINITY; int bidx = 0x7fffffff;
    for (int ci = 0; ci < nc; ++ci) {
        int n = clist[ci] * 256 + tid;
        if (n < V_) {
            const float* wr = fc_w + (size_t)n * 512;
            float d = fc_b[n];
            #pragma unroll 8
            for (int k = 0; k < 512; k += 4) {
                float4 w4 = *(const float4*)&wr[k];
                d += A[k] * w4.x + A[k + 1] * w4.y + A[k + 2] * w4.z + A[k + 3] * w4.w;
            }
            if (d > best || (d == best && n < bidx)) { best = d; bidx = n; }
        }
    }
    sv[tid] = best; si2[tid] = bidx; __syncthreads();
    for (int st = 128; st; st >>= 1) {
        if (tid < st) {
            float o = sv[tid + st]; int oi = si2[tid + st];
            if (o > sv[tid] || (o == sv[tid] && oi < si2[tid])) { sv[tid] = o; si2[tid] = oi; }
        }
        __syncthreads();
    }
    if (tid == 0) dec_in[b] = si2[0];
}

// out[b][t][:] -= logZ[b]   (float4)
__global__ __launch_bounds__(256) void norm_kernel(
    float* __restrict__ outp /* out + t*V_ */, const float* __restrict__ logZ_arr)
{
    int idx = blockIdx.x * 256 + threadIdx.x;    // 64 * 12500
    int b = idx / 12500;
    int j = idx - b * 12500;
    float z = logZ_arr[b];
    float4* p = (float4*)(outp + (size_t)b * LDCV) + j;
    float4 v = *p;
    v.x -= z; v.y -= z; v.z -= z; v.w -= z;
    *p = v;
}

// ---------------------------------------------------------------------------
// Fallback log_softmax (round-1 path, used only if ws too small for fcwb)
// ---------------------------------------------------------------------------
__global__ __launch_bounds__(1024) void lsm_kernel(
    float* __restrict__ out, int t, int* __restrict__ dec_in)
{
    int b = blockIdx.x;
    int tid = threadIdx.x;
    float* row = out + (size_t)b * T_ * V_ + (size_t)t * V_;
    __shared__ float sv[1024];
    __shared__ int si_[1024];

    float lm = -INFINITY;
    int li = 0;
    for (int v = tid; v < V_; v += 1024) {
        float x = row[v];
        if (x > lm) { lm = x; li = v; }
    }
    sv[tid] = lm; si_[tid] = li;
    __syncthreads();
    for (int s = 512; s; s >>= 1) {
        if (tid < s) {
            float o = sv[tid + s]; int oi = si_[tid + s];
            if (o > sv[tid] || (o == sv[tid] && oi < si_[tid])) { sv[tid] = o; si_[tid] = oi; }
        }
        __syncthreads();
    }
    float M = sv[0];
    int amax = si_[0];
    __syncthreads();

    float ls = 0.f;
    for (int v = tid; v < V_; v += 1024) ls += expf(row[v] - M);
    sv[tid] = ls;
    __syncthreads();
    for (int s = 512; s; s >>= 1) {
        if (tid < s) sv[tid] += sv[tid + s];
        __syncthreads();
    }
    float logZ = M + logf(sv[0]);

    for (int v = tid; v < V_; v += 1024) row[v] -= logZ;
    if (tid == 0) dec_in[b] = amax;
}

__global__ __launch_bounds__(256) void final_copy(
    const float* __restrict__ hfin, float* __restrict__ dst)
{
    int idx = blockIdx.x * 256 + threadIdx.x;
    if (idx < B_ * H_) dst[idx] = hfin[idx];
}

// ---------------------------------------------------------------------------
extern "C" void kernel_launch(void* const* d_in, const int* in_sizes, int n_in,
                              void* d_out, int out_size, void* d_ws, size_t ws_size,
                              hipStream_t stream)
{
    const float* enc_hidden = (const float*)d_in[0];
    const float* enc    = (const float*)d_in[3];
    const float* emb    = (const float*)d_in[4];
    const float* w_ih   = (const float*)d_in[5];
    const float* w_hh   = (const float*)d_in[6];
    const float* b_ih   = (const float*)d_in[7];
    const float* b_hh   = (const float*)d_in[8];
    const float* attn_w = (const float*)d_in[9];
    const float* Wa     = (const float*)d_in[10];
    const float* fc_w   = (const float*)d_in[11];
    const float* fc_b   = (const float*)d_in[12];
    float* out = (float*)d_out;
    float* ws  = (float*)d_ws;

    // ws layout (float units)
    size_t off = 0;
    float* WbigT   = ws + off; off += 1572864;
    float* biasBig = ws + off; off += 2048;
    float* awT     = ws + off; off += 262144;
    float* hbuf0   = ws + off; off += 32768;
    float* hbuf1   = ws + off; off += 32768;
    float* gatesP  = ws + off; off += 6 * 64 * 2048;   // 786432
    float* qP      = ws + off; off += 4 * 64 * 512;    // 131072
    float* concatA = ws + off; off += 65536;
    float* cgP     = ws + off; off += 8 * 64 * 512;    // 262144
    float* Abuf    = ws + off; off += 32768;
    u16*   Abufb   = (u16*)(ws + off); off += 16384;
    float* pmax    = ws + off; off += 64 * NCHUNK;
    int*   pidx    = (int*)(ws + off); off += 64 * NCHUNK;
    float* psum    = ws + off; off += 64 * NCHUNK;
    float* logZ_a  = ws + off; off += 64;
    int*   dec_in  = (int*)(ws + off); off += 64;
    u16*   fcwb    = (u16*)(ws + off);
    size_t need_bytes = (off + 12800000) * 4;   // + fcwb (50000*512 bf16)
    const bool big = ws_size >= need_bytes;

    build_wbig<<<6144, 256, 0, stream>>>(w_ih, w_hh, b_ih, b_hh, WbigT, biasBig);
    transpose_aw<<<1024, 256, 0, stream>>>(attn_w, awT);
    init_state<<<128, 256, 0, stream>>>(enc_hidden, hbuf0, dec_in);
    if (big) conv_fcw<<<12500, 256, 0, stream>>>(fc_w, fcwb);

    for (int t = 0; t < T_; ++t) {
        float* hcur = (t & 1) ? hbuf1 : hbuf0;
        float* hnxt = (t & 1) ? hbuf0 : hbuf1;

        // gates = [x|h] @ WbigT^T   (K=768 in 6 chunks of 128)
        gemm64<0><<<dim3(32, 6), 256, 0, stream>>>(
            nullptr, WbigT, gatesP, nullptr, 2048, 768, 128,
            emb, dec_in, hcur, 0);

        combine_kernel<<<64, 512, 0, stream>>>(gatesP, biasBig, hcur, hnxt, concatA);

        // q = h_new @ attn_w   (K=512 in 4 chunks)
        gemm64<1><<<dim3(8, 4), 256, 0, stream>>>(
            hnxt, awT, qP, nullptr, 512, 512, 128,
            nullptr, nullptr, nullptr, 0);

        attn_kernel<<<64, 512, 0, stream>>>(qP, enc, concatA);

        // concat_out_pre = [h_new|ctx] @ Wa^T   (K=1024 in 8 chunks)
        gemm64<1><<<dim3(8, 8), 256, 0, stream>>>(
            concatA, Wa, cgP, nullptr, 512, 1024, 128,
            nullptr, nullptr, nullptr, 0);

        tanh_combine<<<64, 512, 0, stream>>>(cgP, Abuf, Abufb);

        if (big) {
            logits_mfma<<<NCHUNK, 256, 0, stream>>>(
                Abufb, fcwb, fc_b, out + (size_t)t * V_, pmax, pidx, psum);
            szrefine<<<64, 256, 0, stream>>>(
                pmax, pidx, psum, Abuf, fc_w, fc_b, logZ_a, dec_in);
            norm_kernel<<<3125, 256, 0, stream>>>(out + (size_t)t * V_, logZ_a);
        } else {
            gemm64<2><<<dim3(782, 1), 256, 0, stream>>>(
                Abuf, fc_w, out + (size_t)t * V_, fc_b, V_, 512, 512,
                nullptr, nullptr, nullptr, LDCV);
            lsm_kernel<<<64, 1024, 0, stream>>>(out, t, dec_in);
        }
    }

    final_copy<<<128, 256, 0, stream>>>(hbuf0, out + (size_t)B_ * T_ * V_);
}